// Round 2
// baseline (1803.329 us; speedup 1.0000x reference)
//
#include <hip/hip_runtime.h>
#include <hip/hip_bf16.h>

#define TOK 8192      // B*S tokens
#define DD 1024       // D
#define FF 4096       // F
#define EE 8          // experts
#define NPAIR 16384   // TOK*K

typedef __attribute__((ext_vector_type(8))) short short8;
typedef __attribute__((ext_vector_type(4))) float f32x4;

// async global->LDS, 16B per lane. LDS dest must be wave-uniform base (+lane*16 implicit).
__device__ __forceinline__ void async16(const void* g, void* l) {
  __builtin_amdgcn_global_load_lds((const __attribute__((address_space(1))) void*)g,
                                   (__attribute__((address_space(3))) void*)l, 16, 0, 0);
}

__device__ __forceinline__ short bfc(float f) {
  return __builtin_bit_cast(short, (__bf16)f);   // RNE f32->bf16 (hw cvt on gfx950)
}
__device__ __forceinline__ short8 cvt8(f32x4 a, f32x4 b) {
  short8 r;
  r[0]=bfc(a[0]); r[1]=bfc(a[1]); r[2]=bfc(a[2]); r[3]=bfc(a[3]);
  r[4]=bfc(b[0]); r[5]=bfc(b[1]); r[6]=bfc(b[2]); r[7]=bfc(b[3]);
  return r;
}

// ---------------- router: logits -> softmax -> top2 -> per-expert lists ----------------
__global__ __launch_bounds__(64) void router_kernel(const float* __restrict__ x,
    const float* __restrict__ rw, int* __restrict__ counts, int* __restrict__ lists,
    float* __restrict__ gates) {
  const int t = blockIdx.x;
  const int l = threadIdx.x;
  const f32x4* xr = (const f32x4*)(x + (size_t)t * DD);
  f32x4 xv[4];
#pragma unroll
  for (int i = 0; i < 4; i++) xv[i] = xr[l + 64 * i];
  float lg[EE];
#pragma unroll
  for (int e = 0; e < EE; e++) {
    const f32x4* wr = (const f32x4*)(rw + e * DD);
    float s = 0.f;
#pragma unroll
    for (int i = 0; i < 4; i++) {
      f32x4 w = wr[l + 64 * i];
      s += xv[i][0]*w[0] + xv[i][1]*w[1] + xv[i][2]*w[2] + xv[i][3]*w[3];
    }
#pragma unroll
    for (int off = 32; off > 0; off >>= 1) s += __shfl_down(s, off, 64);
    lg[e] = s;
  }
  if (l == 0) {
    float mx = lg[0];
#pragma unroll
    for (int e = 1; e < EE; e++) mx = fmaxf(mx, lg[e]);
    float p[EE]; float den = 0.f;
#pragma unroll
    for (int e = 0; e < EE; e++) { p[e] = expf(lg[e] - mx); den += p[e]; }
    int i1 = 0;
#pragma unroll
    for (int e = 1; e < EE; e++) if (p[e] > p[i1]) i1 = e;   // first max (jax tie order)
    int i2 = (i1 == 0) ? 1 : 0;
#pragma unroll
    for (int e = 0; e < EE; e++) if (e != i1 && p[e] > p[i2]) i2 = e;
    float inv = 1.f / den;
    gates[t*2+0] = p[i1] * inv;
    gates[t*2+1] = p[i2] * inv;
    int p1 = atomicAdd(&counts[i1], 1); lists[i1*TOK + p1] = t*2 + 0;
    int p2 = atomicAdd(&counts[i2], 1); lists[i2*TOK + p2] = t*2 + 1;
  }
}

// ---------------- stage A: h = gelu(x*wg^T+bg) .* (x*w1^T+b1), gathered rows ----------------
// tile 128 rows(pairs) x 128 cols(f), BK=32 f32. f32 LDS tiles, XOR swizzle slot^=(row&7)
// (applied on the per-lane GLOBAL source so global_load_lds dest stays linear; reads XOR back).
__global__ __launch_bounds__(256, 2) void stage_a(
    const float* __restrict__ x, const float* __restrict__ wgw, const float* __restrict__ wgb,
    const float* __restrict__ w1w, const float* __restrict__ w1b,
    const int* __restrict__ counts, const int* __restrict__ lists,
    short* __restrict__ hbuf, int f0chunk, int Fc) {

  const int e = blockIdx.z;
  const int cnt = counts[e];
  const int row0 = blockIdx.x * 128;
  if (row0 >= cnt) return;
  const int fc0 = blockIdx.y * 128;       // chunk-local col base
  const int fg0 = f0chunk + fc0;          // global f base

  __shared__ float lA[128 * 32];
  __shared__ float lBg[128 * 32];
  __shared__ float lB1[128 * 32];
  __shared__ int s_pair[128];

  const int tid = threadIdx.x;
  const int wid = tid >> 6;
  const int lane = tid & 63;

  if (tid < 128) {
    int r = row0 + tid;
    s_pair[tid] = (r < cnt) ? lists[e*TOK + r] : 0;   // clamp invalid to pair 0 (valid mem)
  }
  __syncthreads();

  // staging sources: unit j = p*256+tid (16B units); row=j>>3, physical slot j&7 holds
  // logical slot (j&7)^(row&7)  -> source col = ((j&7)^(row&7))*4 f32
  const float* aSrc[4]; const float* gSrc[4]; const float* oSrc[4];
#pragma unroll
  for (int p = 0; p < 4; p++) {
    int j = p * 256 + tid;
    int r = j >> 3;
    int sl = (j & 7) ^ (r & 7);
    int tok = s_pair[r] >> 1;
    aSrc[p] = x + (size_t)tok * DD + sl * 4;
    int fr = fg0 + r;
    gSrc[p] = wgw + ((size_t)e * FF + fr) * DD + sl * 4;
    oSrc[p] = w1w + ((size_t)e * FF + fr) * DD + sl * 4;
  }

  f32x4 accg[4][4] = {}; f32x4 acc1[4][4] = {};
  const int wr = wid >> 1, wc = wid & 1;

  for (int k0 = 0; k0 < DD; k0 += 32) {
#pragma unroll
    for (int p = 0; p < 4; p++) async16(aSrc[p] + k0, &lA[p*1024 + wid*256]);
#pragma unroll
    for (int p = 0; p < 4; p++) async16(gSrc[p] + k0, &lBg[p*1024 + wid*256]);
#pragma unroll
    for (int p = 0; p < 4; p++) async16(oSrc[p] + k0, &lB1[p*1024 + wid*256]);
    __syncthreads();   // compiler emits vmcnt(0) drain before barrier

    short8 a[4], bg[4], b1[4];
#pragma unroll
    for (int mi = 0; mi < 4; mi++) {
      int r = wr*64 + mi*16 + (lane & 15);
      int g2 = (lane >> 4) * 2;
      const f32x4* Ar = (const f32x4*)&lA[r * 32];
      a[mi] = cvt8(Ar[g2 ^ (r & 7)], Ar[(g2 + 1) ^ (r & 7)]);
    }
#pragma unroll
    for (int ni = 0; ni < 4; ni++) {
      int r = wc*64 + ni*16 + (lane & 15);
      int g2 = (lane >> 4) * 2;
      const f32x4* Bg = (const f32x4*)&lBg[r * 32];
      const f32x4* B1 = (const f32x4*)&lB1[r * 32];
      bg[ni] = cvt8(Bg[g2 ^ (r & 7)], Bg[(g2 + 1) ^ (r & 7)]);
      b1[ni] = cvt8(B1[g2 ^ (r & 7)], B1[(g2 + 1) ^ (r & 7)]);
    }
#pragma unroll
    for (int mi = 0; mi < 4; mi++)
#pragma unroll
      for (int ni = 0; ni < 4; ni++) {
        accg[mi][ni] = __builtin_amdgcn_mfma_f32_16x16x32_bf16(a[mi], bg[ni], accg[mi][ni], 0, 0, 0);
        acc1[mi][ni] = __builtin_amdgcn_mfma_f32_16x16x32_bf16(a[mi], b1[ni], acc1[mi][ni], 0, 0, 0);
      }
    __syncthreads();
  }

  // epilogue: h = gelu(vg) * v1 -> bf16, rows scattered by pair id
  const float* wgb_e = wgb + e * FF;
  const float* w1b_e = w1b + e * FF;
#pragma unroll
  for (int mi = 0; mi < 4; mi++) {
    int trb = wr*64 + mi*16 + ((lane >> 4) << 2);
#pragma unroll
    for (int ni = 0; ni < 4; ni++) {
      int c = wc*64 + ni*16 + (lane & 15);
      float bgv = wgb_e[fg0 + c];
      float b1v = w1b_e[fg0 + c];
#pragma unroll
      for (int j = 0; j < 4; j++) {
        int tr = trb + j;
        if (row0 + tr < cnt) {
          int pair = s_pair[tr];
          float hg = accg[mi][ni][j] + bgv;
          float h1 = acc1[mi][ni][j] + b1v;
          float gl = 0.5f * hg * (1.f + erff(hg * 0.70710678118f));
          hbuf[(size_t)pair * Fc + fc0 + c] = bfc(gl * h1);
        }
      }
    }
  }
}

// ---------------- stage B: out += gate * (h * w2^T (+ b2)) ----------------
// tile 128 rows(pairs) x 128 cols(d), BK=64. A=h bf16 (128B rows, 8 slots),
// B=w2 f32 (256B rows, 16 slots); same XOR swizzle slot^=(row&7).
__global__ __launch_bounds__(256, 2) void stage_b(
    const short* __restrict__ hbuf, const float* __restrict__ w2w, const float* __restrict__ w2b,
    const int* __restrict__ counts, const int* __restrict__ lists, const float* __restrict__ gates,
    float* __restrict__ out, int f0chunk, int Fc, int addbias) {

  const int e = blockIdx.z;
  const int cnt = counts[e];
  const int row0 = blockIdx.x * 128;
  if (row0 >= cnt) return;
  const int d0 = blockIdx.y * 128;

  __shared__ short lA[128 * 64];   // 16 KB bf16
  __shared__ float lB[128 * 64];   // 32 KB f32
  __shared__ int s_pair[128];

  const int tid = threadIdx.x;
  const int wid = tid >> 6;
  const int lane = tid & 63;

  if (tid < 128) {
    int r = row0 + tid;
    s_pair[tid] = (r < cnt) ? lists[e*TOK + r] : 0;
  }
  __syncthreads();

  const short* aSrc[4];
#pragma unroll
  for (int p = 0; p < 4; p++) {
    int j = p * 256 + tid;
    int r = j >> 3;                 // 8 x 16B units per 128B row
    int sl = (j & 7) ^ (r & 7);
    aSrc[p] = hbuf + (size_t)s_pair[r] * Fc + sl * 8;
  }
  const float* bSrc[8];
#pragma unroll
  for (int p = 0; p < 8; p++) {
    int j = p * 256 + tid;
    int r = j >> 4;                 // 16 x 16B units per 256B row
    int sl = (j & 15) ^ (r & 7);
    bSrc[p] = w2w + ((size_t)e * DD + d0 + r) * FF + f0chunk + sl * 4;
  }

  f32x4 acc[4][4] = {};
  const int wr = wid >> 1, wc = wid & 1;

  for (int kf = 0; kf < Fc; kf += 64) {
#pragma unroll
    for (int p = 0; p < 4; p++) async16(aSrc[p] + kf, &lA[p*2048 + wid*512]);
#pragma unroll
    for (int p = 0; p < 8; p++) async16(bSrc[p] + kf, &lB[p*1024 + wid*256]);
    __syncthreads();

#pragma unroll
    for (int kk = 0; kk < 2; kk++) {
      short8 a[4]; short8 b[4];
#pragma unroll
      for (int mi = 0; mi < 4; mi++) {
        int r = wr*64 + mi*16 + (lane & 15);
        int u = (kk*4 + (lane >> 4)) ^ (r & 7);
        a[mi] = ((const short8*)(lA + r * 64))[u];
      }
#pragma unroll
      for (int ni = 0; ni < 4; ni++) {
        int r = wc*64 + ni*16 + (lane & 15);
        int g2 = (kk*4 + (lane >> 4)) * 2;
        const f32x4* Br = (const f32x4*)(lB + r * 64);
        b[ni] = cvt8(Br[g2 ^ (r & 7)], Br[(g2 + 1) ^ (r & 7)]);
      }
#pragma unroll
      for (int mi = 0; mi < 4; mi++)
#pragma unroll
        for (int ni = 0; ni < 4; ni++)
          acc[mi][ni] = __builtin_amdgcn_mfma_f32_16x16x32_bf16(a[mi], b[ni], acc[mi][ni], 0, 0, 0);
    }
    __syncthreads();
  }

  const float* w2b_e = w2b + e * DD;
#pragma unroll
  for (int mi = 0; mi < 4; mi++) {
    int trb = wr*64 + mi*16 + ((lane >> 4) << 2);
#pragma unroll
    for (int j = 0; j < 4; j++) {
      int tr = trb + j;
      if (row0 + tr < cnt) {
        int pair = s_pair[tr];
        int t = pair >> 1;
        float gt = gates[pair];
        float* orow = out + (size_t)t * DD;
#pragma unroll
        for (int ni = 0; ni < 4; ni++) {
          int d = d0 + wc*64 + ni*16 + (lane & 15);   // FIX: add d0 (was tile-local!)
          float v = acc[mi][ni][j] * gt;
          if (addbias) v += w2b_e[d] * gt;
          atomicAdd(orow + d, v);
        }
      }
    }
  }
}

extern "C" void kernel_launch(void* const* d_in, const int* in_sizes, int n_in,
                              void* d_out, int out_size, void* d_ws, size_t ws_size,
                              hipStream_t stream) {
  const float* x   = (const float*)d_in[0];
  const float* rw  = (const float*)d_in[1];
  const float* w1w = (const float*)d_in[2];
  const float* w1b = (const float*)d_in[3];
  const float* w2w = (const float*)d_in[4];
  const float* w2b = (const float*)d_in[5];
  const float* wgw = (const float*)d_in[6];
  const float* wgb = (const float*)d_in[7];
  float* out = (float*)d_out;

  char* ws = (char*)d_ws;
  int*   counts = (int*)ws;
  int*   lists  = (int*)(ws + 128);
  float* gates  = (float*)(ws + 128 + EE*TOK*4);
  short* hbuf   = (short*)(ws + 128 + EE*TOK*4 + NPAIR*4);
  const size_t base = 128 + (size_t)EE*TOK*4 + (size_t)NPAIR*4;

  // F-chunk: largest h chunk that fits workspace
  int Fc = 128;
  const int cands[6] = {4096, 2048, 1024, 512, 256, 128};
  for (int i = 0; i < 6; i++) {
    if (base + (size_t)NPAIR * cands[i] * 2 <= ws_size) { Fc = cands[i]; break; }
  }

  hipMemsetAsync(counts, 0, 128, stream);
  hipMemsetAsync(out, 0, (size_t)TOK * DD * 4, stream);

  router_kernel<<<dim3(TOK), dim3(64), 0, stream>>>(x, rw, counts, lists, gates);

  for (int f0 = 0; f0 < FF; f0 += Fc) {
    dim3 ga(64, Fc / 128, EE);
    stage_a<<<ga, dim3(256), 0, stream>>>(x, wgw, wgb, w1w, w1b, counts, lists, hbuf, f0, Fc);
    dim3 gb(64, DD / 128, EE);
    stage_b<<<gb, dim3(256), 0, stream>>>(hbuf, w2w, w2b, counts, lists, gates, out, f0, Fc, f0 == 0);
  }
}

// Round 3
// 1353.160 us; speedup vs baseline: 1.3327x; 1.3327x over previous
//
#include <hip/hip_runtime.h>
#include <hip/hip_bf16.h>

#define TOK 8192      // B*S tokens
#define DD 1024       // D
#define FF 4096       // F
#define EE 8          // experts
#define NPAIR 16384   // TOK*K

typedef __attribute__((ext_vector_type(8))) short short8;
typedef __attribute__((ext_vector_type(4))) float f32x4;

// async global->LDS, 16B per lane. LDS dest = wave-uniform base + lane*16 (linear).
__device__ __forceinline__ void async16(const void* g, void* l) {
  __builtin_amdgcn_global_load_lds((const __attribute__((address_space(1))) void*)g,
                                   (__attribute__((address_space(3))) void*)l, 16, 0, 0);
}

__device__ __forceinline__ short bfc(float f) {
  return __builtin_bit_cast(short, (__bf16)f);   // RNE f32->bf16
}
__device__ __forceinline__ short8 cvt8(f32x4 a, f32x4 b) {
  short8 r;
  r[0]=bfc(a[0]); r[1]=bfc(a[1]); r[2]=bfc(a[2]); r[3]=bfc(a[3]);
  r[4]=bfc(b[0]); r[5]=bfc(b[1]); r[6]=bfc(b[2]); r[7]=bfc(b[3]);
  return r;
}

// ---------------- f32 -> bf16 pack (grid-stride, 8 elems/thread/iter) ----------------
__global__ __launch_bounds__(256) void cvt_bf16_kernel(const float* __restrict__ src,
                                                       short* __restrict__ dst, int n8) {
  int i = blockIdx.x * 256 + threadIdx.x;
  const int stride = gridDim.x * 256;
  for (; i < n8; i += stride) {
    f32x4 a = ((const f32x4*)src)[2*i];
    f32x4 b = ((const f32x4*)src)[2*i + 1];
    ((short8*)dst)[i] = cvt8(a, b);
  }
}

// ---------------- router: logits -> softmax -> top2 -> per-expert lists ----------------
__global__ __launch_bounds__(64) void router_kernel(const float* __restrict__ x,
    const float* __restrict__ rw, int* __restrict__ counts, int* __restrict__ lists,
    float* __restrict__ gates) {
  const int t = blockIdx.x;
  const int l = threadIdx.x;
  const f32x4* xr = (const f32x4*)(x + (size_t)t * DD);
  f32x4 xv[4];
#pragma unroll
  for (int i = 0; i < 4; i++) xv[i] = xr[l + 64 * i];
  float lg[EE];
#pragma unroll
  for (int e = 0; e < EE; e++) {
    const f32x4* wr = (const f32x4*)(rw + e * DD);
    float s = 0.f;
#pragma unroll
    for (int i = 0; i < 4; i++) {
      f32x4 w = wr[l + 64 * i];
      s += xv[i][0]*w[0] + xv[i][1]*w[1] + xv[i][2]*w[2] + xv[i][3]*w[3];
    }
#pragma unroll
    for (int off = 32; off > 0; off >>= 1) s += __shfl_down(s, off, 64);
    lg[e] = s;
  }
  if (l == 0) {
    float mx = lg[0];
#pragma unroll
    for (int e = 1; e < EE; e++) mx = fmaxf(mx, lg[e]);
    float p[EE]; float den = 0.f;
#pragma unroll
    for (int e = 0; e < EE; e++) { p[e] = expf(lg[e] - mx); den += p[e]; }
    int i1 = 0;
#pragma unroll
    for (int e = 1; e < EE; e++) if (p[e] > p[i1]) i1 = e;
    int i2 = (i1 == 0) ? 1 : 0;
#pragma unroll
    for (int e = 0; e < EE; e++) if (e != i1 && p[e] > p[i2]) i2 = e;
    float inv = 1.f / den;
    gates[t*2+0] = p[i1] * inv;
    gates[t*2+1] = p[i2] * inv;
    int p1 = atomicAdd(&counts[i1], 1); lists[i1*TOK + p1] = t*2 + 0;
    int p2 = atomicAdd(&counts[i2], 1); lists[i2*TOK + p2] = t*2 + 1;
  }
}

// ================= bf16 fast path =================
// stage A: h = gelu(x*wg^T+bg) .* (x*w1^T+b1). Tiles 128x128, BK=64 bf16.
// LDS rows = 64 bf16 = 8x16B units; XOR swizzle unit^=(row&7), applied on the per-lane
// GLOBAL source (LDS dest linear for global_load_lds) and again on ds_read (rule #21).
__global__ __launch_bounds__(256, 2) void stage_a_bf(
    const short* __restrict__ xb, const short* __restrict__ wgwb, const float* __restrict__ wgb,
    const short* __restrict__ w1wb, const float* __restrict__ w1b,
    const int* __restrict__ counts, const int* __restrict__ lists,
    short* __restrict__ hbuf, int f0chunk, int Fc) {

  const int e = blockIdx.z;
  const int cnt = counts[e];
  const int row0 = blockIdx.x * 128;
  if (row0 >= cnt) return;
  const int fc0 = blockIdx.y * 128;
  const int fg0 = f0chunk + fc0;

  __shared__ short lA[128 * 64];   // 16 KB
  __shared__ short lBg[128 * 64];
  __shared__ short lB1[128 * 64];
  __shared__ int s_pair[128];

  const int tid = threadIdx.x;
  const int wid = tid >> 6;
  const int lane = tid & 63;

  if (tid < 128) {
    int r = row0 + tid;
    s_pair[tid] = (r < cnt) ? lists[e*TOK + r] : 0;
  }
  __syncthreads();

  // staging: unit j = p*256+tid in [0,1024); row r=j>>3, phys slot j&7 holds logical (j&7)^(r&7)
  const short* aSrc[4]; const short* gSrc[4]; const short* oSrc[4];
#pragma unroll
  for (int p = 0; p < 4; p++) {
    int j = p * 256 + tid;
    int r = j >> 3;
    int sl = (j & 7) ^ (r & 7);
    int tok = s_pair[r] >> 1;
    aSrc[p] = xb + (size_t)tok * DD + sl * 8;
    int fr = fg0 + r;
    gSrc[p] = wgwb + ((size_t)e * FF + fr) * DD + sl * 8;
    oSrc[p] = w1wb + ((size_t)e * FF + fr) * DD + sl * 8;
  }

  f32x4 accg[4][4] = {}; f32x4 acc1[4][4] = {};
  const int wr = wid >> 1, wc = wid & 1;

  for (int k0 = 0; k0 < DD; k0 += 64) {
#pragma unroll
    for (int p = 0; p < 4; p++) async16(aSrc[p] + k0, &lA[p*2048 + wid*512]);
#pragma unroll
    for (int p = 0; p < 4; p++) async16(gSrc[p] + k0, &lBg[p*2048 + wid*512]);
#pragma unroll
    for (int p = 0; p < 4; p++) async16(oSrc[p] + k0, &lB1[p*2048 + wid*512]);
    __syncthreads();

#pragma unroll
    for (int kk = 0; kk < 2; kk++) {
      short8 a[4], bg[4], b1[4];
#pragma unroll
      for (int mi = 0; mi < 4; mi++) {
        int r = wr*64 + mi*16 + (lane & 15);
        int u = (kk*4 + (lane >> 4)) ^ (r & 7);
        a[mi] = ((const short8*)(lA + r * 64))[u];
      }
#pragma unroll
      for (int ni = 0; ni < 4; ni++) {
        int r = wc*64 + ni*16 + (lane & 15);
        int u = (kk*4 + (lane >> 4)) ^ (r & 7);
        bg[ni] = ((const short8*)(lBg + r * 64))[u];
        b1[ni] = ((const short8*)(lB1 + r * 64))[u];
      }
#pragma unroll
      for (int mi = 0; mi < 4; mi++)
#pragma unroll
        for (int ni = 0; ni < 4; ni++) {
          accg[mi][ni] = __builtin_amdgcn_mfma_f32_16x16x32_bf16(a[mi], bg[ni], accg[mi][ni], 0, 0, 0);
          acc1[mi][ni] = __builtin_amdgcn_mfma_f32_16x16x32_bf16(a[mi], b1[ni], acc1[mi][ni], 0, 0, 0);
        }
    }
    __syncthreads();
  }

  const float* wgb_e = wgb + e * FF;
  const float* w1b_e = w1b + e * FF;
#pragma unroll
  for (int mi = 0; mi < 4; mi++) {
    int trb = wr*64 + mi*16 + ((lane >> 4) << 2);
#pragma unroll
    for (int ni = 0; ni < 4; ni++) {
      int c = wc*64 + ni*16 + (lane & 15);
      float bgv = wgb_e[fg0 + c];
      float b1v = w1b_e[fg0 + c];
#pragma unroll
      for (int j = 0; j < 4; j++) {
        int tr = trb + j;
        if (row0 + tr < cnt) {
          int pair = s_pair[tr];
          float hg = accg[mi][ni][j] + bgv;
          float h1 = acc1[mi][ni][j] + b1v;
          float gl = 0.5f * hg * (1.f + erff(hg * 0.70710678118f));
          hbuf[(size_t)pair * Fc + fc0 + c] = bfc(gl * h1);
        }
      }
    }
  }
}

// stage B: out += gate * (h * w2^T (+ b2)). Tiles 128x128, BK=64 bf16 both sides.
__global__ __launch_bounds__(256, 2) void stage_b_bf(
    const short* __restrict__ hbuf, const short* __restrict__ w2wb, const float* __restrict__ w2b,
    const int* __restrict__ counts, const int* __restrict__ lists, const float* __restrict__ gates,
    float* __restrict__ out, int f0chunk, int Fc, int addbias) {

  const int e = blockIdx.z;
  const int cnt = counts[e];
  const int row0 = blockIdx.x * 128;
  if (row0 >= cnt) return;
  const int d0 = blockIdx.y * 128;

  __shared__ short lA[128 * 64];
  __shared__ short lB[128 * 64];
  __shared__ int s_pair[128];

  const int tid = threadIdx.x;
  const int wid = tid >> 6;
  const int lane = tid & 63;

  if (tid < 128) {
    int r = row0 + tid;
    s_pair[tid] = (r < cnt) ? lists[e*TOK + r] : 0;
  }
  __syncthreads();

  const short* aSrc[4]; const short* bSrc[4];
#pragma unroll
  for (int p = 0; p < 4; p++) {
    int j = p * 256 + tid;
    int r = j >> 3;
    int sl = (j & 7) ^ (r & 7);
    aSrc[p] = hbuf + (size_t)s_pair[r] * Fc + sl * 8;
    bSrc[p] = w2wb + ((size_t)e * DD + d0 + r) * FF + f0chunk + sl * 8;
  }

  f32x4 acc[4][4] = {};
  const int wr = wid >> 1, wc = wid & 1;

  for (int kf = 0; kf < Fc; kf += 64) {
#pragma unroll
    for (int p = 0; p < 4; p++) async16(aSrc[p] + kf, &lA[p*2048 + wid*512]);
#pragma unroll
    for (int p = 0; p < 4; p++) async16(bSrc[p] + kf, &lB[p*2048 + wid*512]);
    __syncthreads();

#pragma unroll
    for (int kk = 0; kk < 2; kk++) {
      short8 a[4], b[4];
#pragma unroll
      for (int mi = 0; mi < 4; mi++) {
        int r = wr*64 + mi*16 + (lane & 15);
        int u = (kk*4 + (lane >> 4)) ^ (r & 7);
        a[mi] = ((const short8*)(lA + r * 64))[u];
      }
#pragma unroll
      for (int ni = 0; ni < 4; ni++) {
        int r = wc*64 + ni*16 + (lane & 15);
        int u = (kk*4 + (lane >> 4)) ^ (r & 7);
        b[ni] = ((const short8*)(lB + r * 64))[u];
      }
#pragma unroll
      for (int mi = 0; mi < 4; mi++)
#pragma unroll
        for (int ni = 0; ni < 4; ni++)
          acc[mi][ni] = __builtin_amdgcn_mfma_f32_16x16x32_bf16(a[mi], b[ni], acc[mi][ni], 0, 0, 0);
    }
    __syncthreads();
  }

  const float* w2b_e = w2b + e * DD;
#pragma unroll
  for (int mi = 0; mi < 4; mi++) {
    int trb = wr*64 + mi*16 + ((lane >> 4) << 2);
#pragma unroll
    for (int j = 0; j < 4; j++) {
      int tr = trb + j;
      if (row0 + tr < cnt) {
        int pair = s_pair[tr];
        int t = pair >> 1;
        float gt = gates[pair];
        float* orow = out + (size_t)t * DD;
#pragma unroll
        for (int ni = 0; ni < 4; ni++) {
          int d = d0 + wc*64 + ni*16 + (lane & 15);
          float v = acc[mi][ni][j] * gt;
          if (addbias) v += w2b_e[d] * gt;
          atomicAdd(orow + d, v);
        }
      }
    }
  }
}

// ================= legacy f32 path (fallback if ws too small for bf16 weights) =================
__global__ __launch_bounds__(256, 2) void stage_a_f32(
    const float* __restrict__ x, const float* __restrict__ wgw, const float* __restrict__ wgb,
    const float* __restrict__ w1w, const float* __restrict__ w1b,
    const int* __restrict__ counts, const int* __restrict__ lists,
    short* __restrict__ hbuf, int f0chunk, int Fc) {

  const int e = blockIdx.z;
  const int cnt = counts[e];
  const int row0 = blockIdx.x * 128;
  if (row0 >= cnt) return;
  const int fc0 = blockIdx.y * 128;
  const int fg0 = f0chunk + fc0;

  __shared__ float lA[128 * 32];
  __shared__ float lBg[128 * 32];
  __shared__ float lB1[128 * 32];
  __shared__ int s_pair[128];

  const int tid = threadIdx.x;
  const int wid = tid >> 6;
  const int lane = tid & 63;

  if (tid < 128) {
    int r = row0 + tid;
    s_pair[tid] = (r < cnt) ? lists[e*TOK + r] : 0;
  }
  __syncthreads();

  const float* aSrc[4]; const float* gSrc[4]; const float* oSrc[4];
#pragma unroll
  for (int p = 0; p < 4; p++) {
    int j = p * 256 + tid;
    int r = j >> 3;
    int sl = (j & 7) ^ (r & 7);
    int tok = s_pair[r] >> 1;
    aSrc[p] = x + (size_t)tok * DD + sl * 4;
    int fr = fg0 + r;
    gSrc[p] = wgw + ((size_t)e * FF + fr) * DD + sl * 4;
    oSrc[p] = w1w + ((size_t)e * FF + fr) * DD + sl * 4;
  }

  f32x4 accg[4][4] = {}; f32x4 acc1[4][4] = {};
  const int wr = wid >> 1, wc = wid & 1;

  for (int k0 = 0; k0 < DD; k0 += 32) {
#pragma unroll
    for (int p = 0; p < 4; p++) async16(aSrc[p] + k0, &lA[p*1024 + wid*256]);
#pragma unroll
    for (int p = 0; p < 4; p++) async16(gSrc[p] + k0, &lBg[p*1024 + wid*256]);
#pragma unroll
    for (int p = 0; p < 4; p++) async16(oSrc[p] + k0, &lB1[p*1024 + wid*256]);
    __syncthreads();

    short8 a[4], bg[4], b1[4];
#pragma unroll
    for (int mi = 0; mi < 4; mi++) {
      int r = wr*64 + mi*16 + (lane & 15);
      int g2 = (lane >> 4) * 2;
      const f32x4* Ar = (const f32x4*)&lA[r * 32];
      a[mi] = cvt8(Ar[g2 ^ (r & 7)], Ar[(g2 + 1) ^ (r & 7)]);
    }
#pragma unroll
    for (int ni = 0; ni < 4; ni++) {
      int r = wc*64 + ni*16 + (lane & 15);
      int g2 = (lane >> 4) * 2;
      const f32x4* Bg = (const f32x4*)&lBg[r * 32];
      const f32x4* B1 = (const f32x4*)&lB1[r * 32];
      bg[ni] = cvt8(Bg[g2 ^ (r & 7)], Bg[(g2 + 1) ^ (r & 7)]);
      b1[ni] = cvt8(B1[g2 ^ (r & 7)], B1[(g2 + 1) ^ (r & 7)]);
    }
#pragma unroll
    for (int mi = 0; mi < 4; mi++)
#pragma unroll
      for (int ni = 0; ni < 4; ni++) {
        accg[mi][ni] = __builtin_amdgcn_mfma_f32_16x16x32_bf16(a[mi], bg[ni], accg[mi][ni], 0, 0, 0);
        acc1[mi][ni] = __builtin_amdgcn_mfma_f32_16x16x32_bf16(a[mi], b1[ni], acc1[mi][ni], 0, 0, 0);
      }
    __syncthreads();
  }

  const float* wgb_e = wgb + e * FF;
  const float* w1b_e = w1b + e * FF;
#pragma unroll
  for (int mi = 0; mi < 4; mi++) {
    int trb = wr*64 + mi*16 + ((lane >> 4) << 2);
#pragma unroll
    for (int ni = 0; ni < 4; ni++) {
      int c = wc*64 + ni*16 + (lane & 15);
      float bgv = wgb_e[fg0 + c];
      float b1v = w1b_e[fg0 + c];
#pragma unroll
      for (int j = 0; j < 4; j++) {
        int tr = trb + j;
        if (row0 + tr < cnt) {
          int pair = s_pair[tr];
          float hg = accg[mi][ni][j] + bgv;
          float h1 = acc1[mi][ni][j] + b1v;
          float gl = 0.5f * hg * (1.f + erff(hg * 0.70710678118f));
          hbuf[(size_t)pair * Fc + fc0 + c] = bfc(gl * h1);
        }
      }
    }
  }
}

__global__ __launch_bounds__(256, 2) void stage_b_f32(
    const short* __restrict__ hbuf, const float* __restrict__ w2w, const float* __restrict__ w2b,
    const int* __restrict__ counts, const int* __restrict__ lists, const float* __restrict__ gates,
    float* __restrict__ out, int f0chunk, int Fc, int addbias) {

  const int e = blockIdx.z;
  const int cnt = counts[e];
  const int row0 = blockIdx.x * 128;
  if (row0 >= cnt) return;
  const int d0 = blockIdx.y * 128;

  __shared__ short lA[128 * 64];
  __shared__ float lB[128 * 64];
  __shared__ int s_pair[128];

  const int tid = threadIdx.x;
  const int wid = tid >> 6;
  const int lane = tid & 63;

  if (tid < 128) {
    int r = row0 + tid;
    s_pair[tid] = (r < cnt) ? lists[e*TOK + r] : 0;
  }
  __syncthreads();

  const short* aSrc[4];
#pragma unroll
  for (int p = 0; p < 4; p++) {
    int j = p * 256 + tid;
    int r = j >> 3;
    int sl = (j & 7) ^ (r & 7);
    aSrc[p] = hbuf + (size_t)s_pair[r] * Fc + sl * 8;
  }
  const float* bSrc[8];
#pragma unroll
  for (int p = 0; p < 8; p++) {
    int j = p * 256 + tid;
    int r = j >> 4;
    int sl = (j & 15) ^ (r & 7);
    bSrc[p] = w2w + ((size_t)e * DD + d0 + r) * FF + f0chunk + sl * 4;
  }

  f32x4 acc[4][4] = {};
  const int wr = wid >> 1, wc = wid & 1;

  for (int kf = 0; kf < Fc; kf += 64) {
#pragma unroll
    for (int p = 0; p < 4; p++) async16(aSrc[p] + kf, &lA[p*2048 + wid*512]);
#pragma unroll
    for (int p = 0; p < 8; p++) async16(bSrc[p] + kf, &lB[p*1024 + wid*256]);
    __syncthreads();

#pragma unroll
    for (int kk = 0; kk < 2; kk++) {
      short8 a[4]; short8 b[4];
#pragma unroll
      for (int mi = 0; mi < 4; mi++) {
        int r = wr*64 + mi*16 + (lane & 15);
        int u = (kk*4 + (lane >> 4)) ^ (r & 7);
        a[mi] = ((const short8*)(lA + r * 64))[u];
      }
#pragma unroll
      for (int ni = 0; ni < 4; ni++) {
        int r = wc*64 + ni*16 + (lane & 15);
        int g2 = (kk*4 + (lane >> 4)) * 2;
        const f32x4* Br = (const f32x4*)(lB + r * 64);
        b[ni] = cvt8(Br[g2 ^ (r & 7)], Br[(g2 + 1) ^ (r & 7)]);
      }
#pragma unroll
      for (int mi = 0; mi < 4; mi++)
#pragma unroll
        for (int ni = 0; ni < 4; ni++)
          acc[mi][ni] = __builtin_amdgcn_mfma_f32_16x16x32_bf16(a[mi], b[ni], acc[mi][ni], 0, 0, 0);
    }
    __syncthreads();
  }

  const float* w2b_e = w2b + e * DD;
#pragma unroll
  for (int mi = 0; mi < 4; mi++) {
    int trb = wr*64 + mi*16 + ((lane >> 4) << 2);
#pragma unroll
    for (int j = 0; j < 4; j++) {
      int tr = trb + j;
      if (row0 + tr < cnt) {
        int pair = s_pair[tr];
        int t = pair >> 1;
        float gt = gates[pair];
        float* orow = out + (size_t)t * DD;
#pragma unroll
        for (int ni = 0; ni < 4; ni++) {
          int d = d0 + wc*64 + ni*16 + (lane & 15);
          float v = acc[mi][ni][j] * gt;
          if (addbias) v += w2b_e[d] * gt;
          atomicAdd(orow + d, v);
        }
      }
    }
  }
}

extern "C" void kernel_launch(void* const* d_in, const int* in_sizes, int n_in,
                              void* d_out, int out_size, void* d_ws, size_t ws_size,
                              hipStream_t stream) {
  const float* x   = (const float*)d_in[0];
  const float* rw  = (const float*)d_in[1];
  const float* w1w = (const float*)d_in[2];
  const float* w1b = (const float*)d_in[3];
  const float* w2w = (const float*)d_in[4];
  const float* w2b = (const float*)d_in[5];
  const float* wgw = (const float*)d_in[6];
  const float* wgb = (const float*)d_in[7];
  float* out = (float*)d_out;

  char* ws = (char*)d_ws;
  size_t off = 0;
  int* counts = (int*)(ws + off); off += 128;
  int* lists  = (int*)(ws + off); off += (size_t)EE * TOK * 4;
  float* gates = (float*)(ws + off); off += (size_t)NPAIR * 4;
  const size_t base0 = off;

  const size_t WELEM = (size_t)EE * FF * DD;          // per weight tensor elems
  const size_t bf_need = base0 + (size_t)TOK*DD*2 + 3*WELEM*2;  // xb + 3 weights bf16

  hipMemsetAsync(counts, 0, 128, stream);
  hipMemsetAsync(out, 0, (size_t)TOK * DD * 4, stream);
  router_kernel<<<dim3(TOK), dim3(64), 0, stream>>>(x, rw, counts, lists, gates);

  const int cands[6] = {4096, 2048, 1024, 512, 256, 128};

  if (bf_need + (size_t)NPAIR * 128 * 2 <= ws_size) {
    // ---- bf16 path ----
    off = base0;
    short* xb   = (short*)(ws + off); off += (size_t)TOK * DD * 2;
    short* wgwb = (short*)(ws + off); off += WELEM * 2;
    short* w1wb = (short*)(ws + off); off += WELEM * 2;
    short* w2wb = (short*)(ws + off); off += WELEM * 2;
    short* hbuf = (short*)(ws + off);

    int Fc = 128;
    for (int i = 0; i < 6; i++)
      if (off + (size_t)NPAIR * cands[i] * 2 <= ws_size) { Fc = cands[i]; break; }

    cvt_bf16_kernel<<<dim3(2048), dim3(256), 0, stream>>>(x,   xb,   (int)(TOK*DD/8));
    cvt_bf16_kernel<<<dim3(2048), dim3(256), 0, stream>>>(wgw, wgwb, (int)(WELEM/8));
    cvt_bf16_kernel<<<dim3(2048), dim3(256), 0, stream>>>(w1w, w1wb, (int)(WELEM/8));
    cvt_bf16_kernel<<<dim3(2048), dim3(256), 0, stream>>>(w2w, w2wb, (int)(WELEM/8));

    for (int f0 = 0; f0 < FF; f0 += Fc) {
      dim3 ga(64, Fc / 128, EE);
      stage_a_bf<<<ga, dim3(256), 0, stream>>>(xb, wgwb, wgb, w1wb, w1b, counts, lists, hbuf, f0, Fc);
      dim3 gb(64, DD / 128, EE);
      stage_b_bf<<<gb, dim3(256), 0, stream>>>(hbuf, w2wb, w2b, counts, lists, gates, out, f0, Fc, f0 == 0);
    }
  } else {
    // ---- legacy f32 path ----
    short* hbuf = (short*)(ws + base0);
    int Fc = 128;
    for (int i = 0; i < 6; i++)
      if (base0 + (size_t)NPAIR * cands[i] * 2 <= ws_size) { Fc = cands[i]; break; }

    for (int f0 = 0; f0 < FF; f0 += Fc) {
      dim3 ga(64, Fc / 128, EE);
      stage_a_f32<<<ga, dim3(256), 0, stream>>>(x, wgw, wgb, w1w, w1b, counts, lists, hbuf, f0, Fc);
      dim3 gb(64, DD / 128, EE);
      stage_b_f32<<<gb, dim3(256), 0, stream>>>(hbuf, w2w, w2b, counts, lists, gates, out, f0, Fc, f0 == 0);
    }
  }
}

// Round 4
// 1190.788 us; speedup vs baseline: 1.5144x; 1.1364x over previous
//
#include <hip/hip_runtime.h>
#include <hip/hip_bf16.h>

#define TOK 8192      // B*S tokens
#define DD 1024       // D
#define FF 4096       // F
#define EE 8          // experts
#define NPAIR 16384   // TOK*K

typedef __attribute__((ext_vector_type(8))) short short8;
typedef __attribute__((ext_vector_type(4))) short short4v;
typedef __attribute__((ext_vector_type(4))) float f32x4;

#define WAIT_VM8()  asm volatile("s_waitcnt vmcnt(8)" ::: "memory")
#define WAIT_VM0()  asm volatile("s_waitcnt vmcnt(0)" ::: "memory")
#define BARRIER()   asm volatile("s_barrier" ::: "memory")

// async global->LDS, 16B per lane. LDS dest = wave-uniform base + lane*16 (linear).
__device__ __forceinline__ void async16(const void* g, void* l) {
  __builtin_amdgcn_global_load_lds((const __attribute__((address_space(1))) void*)g,
                                   (__attribute__((address_space(3))) void*)l, 16, 0, 0);
}

__device__ __forceinline__ short bfc(float f) {
  return __builtin_bit_cast(short, (__bf16)f);   // RNE f32->bf16
}
__device__ __forceinline__ short8 cvt8(f32x4 a, f32x4 b) {
  short8 r;
  r[0]=bfc(a[0]); r[1]=bfc(a[1]); r[2]=bfc(a[2]); r[3]=bfc(a[3]);
  r[4]=bfc(b[0]); r[5]=bfc(b[1]); r[6]=bfc(b[2]); r[7]=bfc(b[3]);
  return r;
}

// ---------------- f32 -> bf16 pack (grid-stride) ----------------
__global__ __launch_bounds__(256) void cvt_bf16_kernel(const float* __restrict__ src,
                                                       short* __restrict__ dst, int n8) {
  int i = blockIdx.x * 256 + threadIdx.x;
  const int stride = gridDim.x * 256;
  for (; i < n8; i += stride) {
    f32x4 a = ((const f32x4*)src)[2*i];
    f32x4 b = ((const f32x4*)src)[2*i + 1];
    ((short8*)dst)[i] = cvt8(a, b);
  }
}

// ---------------- router: logits -> softmax -> top2 -> lists; also emits xb (bf16 x) ----------------
__global__ __launch_bounds__(64) void router_kernel(const float* __restrict__ x,
    const float* __restrict__ rw, int* __restrict__ counts, int* __restrict__ lists,
    float* __restrict__ gates, short* __restrict__ xb) {
  const int t = blockIdx.x;
  const int l = threadIdx.x;
  const f32x4* xr = (const f32x4*)(x + (size_t)t * DD);
  f32x4 xv[4];
#pragma unroll
  for (int i = 0; i < 4; i++) xv[i] = xr[l + 64 * i];
  // write bf16 x (coalesced 8B per lane per i)
  short4v* xo = (short4v*)(xb + (size_t)t * DD);
#pragma unroll
  for (int i = 0; i < 4; i++) {
    short4v o; o[0]=bfc(xv[i][0]); o[1]=bfc(xv[i][1]); o[2]=bfc(xv[i][2]); o[3]=bfc(xv[i][3]);
    xo[l + 64 * i] = o;
  }
  float lg[EE];
#pragma unroll
  for (int e = 0; e < EE; e++) {
    const f32x4* wr = (const f32x4*)(rw + e * DD);
    float s = 0.f;
#pragma unroll
    for (int i = 0; i < 4; i++) {
      f32x4 w = wr[l + 64 * i];
      s += xv[i][0]*w[0] + xv[i][1]*w[1] + xv[i][2]*w[2] + xv[i][3]*w[3];
    }
#pragma unroll
    for (int off = 32; off > 0; off >>= 1) s += __shfl_down(s, off, 64);
    lg[e] = s;
  }
  if (l == 0) {
    float mx = lg[0];
#pragma unroll
    for (int e = 1; e < EE; e++) mx = fmaxf(mx, lg[e]);
    float p[EE]; float den = 0.f;
#pragma unroll
    for (int e = 0; e < EE; e++) { p[e] = expf(lg[e] - mx); den += p[e]; }
    int i1 = 0;
#pragma unroll
    for (int e = 1; e < EE; e++) if (p[e] > p[i1]) i1 = e;
    int i2 = (i1 == 0) ? 1 : 0;
#pragma unroll
    for (int e = 0; e < EE; e++) if (e != i1 && p[e] > p[i2]) i2 = e;
    float inv = 1.f / den;
    gates[t*2+0] = p[i1] * inv;
    gates[t*2+1] = p[i2] * inv;
    int p1 = atomicAdd(&counts[i1], 1); lists[i1*TOK + p1] = t*2 + 0;
    int p2 = atomicAdd(&counts[i2], 1); lists[i2*TOK + p2] = t*2 + 1;
  }
}

// ================= stage A (bf16): h = gelu(x*wg^T+bg) .* (x*w1^T+b1) =================
// Tile 256(pairs) x 128(f), BK=64, 8 waves, double-buffered LDS (129KB), counted vmcnt(8).
// XOR swizzle unit^=(row&7) pre-applied to global source; ds_read applies it back.
// XCD swizzle: grid (32,32,8) flattened; each XCD owns one expert's blocks (L2 panel reuse).
#define A_LDS (256*64)
#define B_LDS (128*64)
__global__ __launch_bounds__(512, 2) void stage_a_bf(
    const short* __restrict__ xb, const short* __restrict__ wgwb, const float* __restrict__ wgb,
    const short* __restrict__ w1wb, const float* __restrict__ w1b,
    const int* __restrict__ counts, const int* __restrict__ lists,
    short* __restrict__ hbuf, int f0chunk, int Fc) {

  // bijective XCD swizzle: nwg = 32*32*8 = 8192, q = 1024
  const int lin = blockIdx.x + 32 * (blockIdx.y + 32 * blockIdx.z);
  const int orig = (lin & 7) * 1024 + (lin >> 3);
  const int bx = orig & 31;
  const int by = (orig >> 5) & 31;
  const int e  = orig >> 10;

  const int cnt = counts[e];
  const int row0 = bx * 256;
  if (row0 >= cnt) return;
  const int fc0 = by * 128;
  const int fg0 = f0chunk + fc0;

  __shared__ short lA[2 * A_LDS];    // 64 KB
  __shared__ short lBg[2 * B_LDS];   // 32 KB
  __shared__ short lB1[2 * B_LDS];   // 32 KB
  __shared__ int s_pair[256];

  const int tid = threadIdx.x;
  const int wid = tid >> 6;
  const int lane = tid & 63;

  if (tid < 256) {
    int r = row0 + tid;
    s_pair[tid] = (r < cnt) ? lists[e*TOK + r] : 0;
  }
  __syncthreads();

  // staging sources. A: 2048 16B-units (4/thread); Bg,B1: 1024 units (2/thread).
  // unit j -> row r=j>>3, phys slot j&7 holds logical (j&7)^(r&7).
  const short* aSrc[4]; const short* gSrc[2]; const short* oSrc[2];
#pragma unroll
  for (int p = 0; p < 4; p++) {
    int j = p * 512 + tid;
    int r = j >> 3;
    int sl = (j & 7) ^ (r & 7);
    aSrc[p] = xb + (size_t)(s_pair[r] >> 1) * DD + sl * 8;
  }
#pragma unroll
  for (int p = 0; p < 2; p++) {
    int j = p * 512 + tid;
    int r = j >> 3;            // [0,128)
    int sl = (j & 7) ^ (r & 7);
    gSrc[p] = wgwb + ((size_t)e * FF + fg0 + r) * DD + sl * 8;
    oSrc[p] = w1wb + ((size_t)e * FF + fg0 + r) * DD + sl * 8;
  }

  f32x4 accg[4][4] = {}; f32x4 acc1[4][4] = {};
  const int wr = wid >> 1, wc = wid & 1;   // 4 row-chunks x 2 col-chunks of 64

  // prologue: stage tile 0 into buf 0 (8 async16 per thread)
#pragma unroll
  for (int p = 0; p < 4; p++) async16(aSrc[p], &lA[p*4096 + wid*512]);
#pragma unroll
  for (int p = 0; p < 2; p++) async16(gSrc[p], &lBg[p*4096 + wid*512]);
#pragma unroll
  for (int p = 0; p < 2; p++) async16(oSrc[p], &lB1[p*4096 + wid*512]);

  for (int t = 0; t < 16; t++) {
    const int cur = t & 1;
    if (t < 15) {      // stage tile t+1 into other buffer
      const int nb = cur ^ 1;
      const int k0 = (t + 1) * 64;
#pragma unroll
      for (int p = 0; p < 4; p++) async16(aSrc[p] + k0, &lA[nb*A_LDS + p*4096 + wid*512]);
#pragma unroll
      for (int p = 0; p < 2; p++) async16(gSrc[p] + k0, &lBg[nb*B_LDS + p*4096 + wid*512]);
#pragma unroll
      for (int p = 0; p < 2; p++) async16(oSrc[p] + k0, &lB1[nb*B_LDS + p*4096 + wid*512]);
      WAIT_VM8();
    } else {
      WAIT_VM0();
    }
    BARRIER();   // buf[cur] fully written by all waves

    const short* LA = lA  + cur * A_LDS;
    const short* LG = lBg + cur * B_LDS;
    const short* LO = lB1 + cur * B_LDS;
#pragma unroll
    for (int kk = 0; kk < 2; kk++) {
      short8 a[4], bg[4], b1[4];
#pragma unroll
      for (int mi = 0; mi < 4; mi++) {
        int r = wr*64 + mi*16 + (lane & 15);
        int u = (kk*4 + (lane >> 4)) ^ (r & 7);
        a[mi] = *(const short8*)(LA + r*64 + u*8);
      }
#pragma unroll
      for (int ni = 0; ni < 4; ni++) {
        int r = wc*64 + ni*16 + (lane & 15);
        int u = (kk*4 + (lane >> 4)) ^ (r & 7);
        bg[ni] = *(const short8*)(LG + r*64 + u*8);
        b1[ni] = *(const short8*)(LO + r*64 + u*8);
      }
#pragma unroll
      for (int mi = 0; mi < 4; mi++)
#pragma unroll
        for (int ni = 0; ni < 4; ni++) {
          accg[mi][ni] = __builtin_amdgcn_mfma_f32_16x16x32_bf16(a[mi], bg[ni], accg[mi][ni], 0, 0, 0);
          acc1[mi][ni] = __builtin_amdgcn_mfma_f32_16x16x32_bf16(a[mi], b1[ni], acc1[mi][ni], 0, 0, 0);
        }
    }
    BARRIER();   // all waves done reading buf[cur]; next iter may overwrite
  }

  const float* wgb_e = wgb + e * FF;
  const float* w1b_e = w1b + e * FF;
#pragma unroll
  for (int mi = 0; mi < 4; mi++) {
    int trb = wr*64 + mi*16 + ((lane >> 4) << 2);
#pragma unroll
    for (int ni = 0; ni < 4; ni++) {
      int c = wc*64 + ni*16 + (lane & 15);
      float bgv = wgb_e[fg0 + c];
      float b1v = w1b_e[fg0 + c];
#pragma unroll
      for (int j = 0; j < 4; j++) {
        int tr = trb + j;
        if (row0 + tr < cnt) {
          int pair = s_pair[tr];
          float hg = accg[mi][ni][j] + bgv;
          float h1 = acc1[mi][ni][j] + b1v;
          float gl = 0.5f * hg * (1.f + erff(hg * 0.70710678118f));
          hbuf[(size_t)pair * Fc + fc0 + c] = bfc(gl * h1);
        }
      }
    }
  }
}

// ================= stage B (bf16): out += gate * (h * w2^T (+ b2)) =================
// Tile 128x128, BK=64, 4 waves, double-buffered LDS (65KB -> 2 blocks/CU), counted vmcnt(8).
#define BB_LDS (128*64)
__global__ __launch_bounds__(256, 2) void stage_b_bf(
    const short* __restrict__ hbuf, const short* __restrict__ w2wb, const float* __restrict__ w2b,
    const int* __restrict__ counts, const int* __restrict__ lists, const float* __restrict__ gates,
    float* __restrict__ out, int f0chunk, int Fc, int addbias) {

  // bijective XCD swizzle: nwg = 64*8*8 = 4096, q = 512
  const int lin = blockIdx.x + 64 * (blockIdx.y + 8 * blockIdx.z);
  const int orig = (lin & 7) * 512 + (lin >> 3);
  const int bx = orig & 63;
  const int by = (orig >> 6) & 7;
  const int e  = orig >> 9;

  const int cnt = counts[e];
  const int row0 = bx * 128;
  if (row0 >= cnt) return;
  const int d0 = by * 128;

  __shared__ short lA[2 * BB_LDS];   // 32 KB
  __shared__ short lB[2 * BB_LDS];   // 32 KB
  __shared__ int s_pair[128];

  const int tid = threadIdx.x;
  const int wid = tid >> 6;
  const int lane = tid & 63;

  if (tid < 128) {
    int r = row0 + tid;
    s_pair[tid] = (r < cnt) ? lists[e*TOK + r] : 0;
  }
  __syncthreads();

  const short* aSrc[4]; const short* bSrc[4];
#pragma unroll
  for (int p = 0; p < 4; p++) {
    int j = p * 256 + tid;
    int r = j >> 3;
    int sl = (j & 7) ^ (r & 7);
    aSrc[p] = hbuf + (size_t)s_pair[r] * Fc + sl * 8;
    bSrc[p] = w2wb + ((size_t)e * DD + d0 + r) * FF + f0chunk + sl * 8;
  }

  f32x4 acc[4][4] = {};
  const int wr = wid >> 1, wc = wid & 1;
  const int NT = Fc >> 6;

  // prologue
#pragma unroll
  for (int p = 0; p < 4; p++) async16(aSrc[p], &lA[p*2048 + wid*512]);
#pragma unroll
  for (int p = 0; p < 4; p++) async16(bSrc[p], &lB[p*2048 + wid*512]);

  for (int t = 0; t < NT; t++) {
    const int cur = t & 1;
    if (t + 1 < NT) {
      const int nb = cur ^ 1;
      const int kf = (t + 1) * 64;
#pragma unroll
      for (int p = 0; p < 4; p++) async16(aSrc[p] + kf, &lA[nb*BB_LDS + p*2048 + wid*512]);
#pragma unroll
      for (int p = 0; p < 4; p++) async16(bSrc[p] + kf, &lB[nb*BB_LDS + p*2048 + wid*512]);
      WAIT_VM8();
    } else {
      WAIT_VM0();
    }
    BARRIER();

    const short* LA = lA + cur * BB_LDS;
    const short* LB = lB + cur * BB_LDS;
#pragma unroll
    for (int kk = 0; kk < 2; kk++) {
      short8 a[4], b[4];
#pragma unroll
      for (int mi = 0; mi < 4; mi++) {
        int r = wr*64 + mi*16 + (lane & 15);
        int u = (kk*4 + (lane >> 4)) ^ (r & 7);
        a[mi] = *(const short8*)(LA + r*64 + u*8);
      }
#pragma unroll
      for (int ni = 0; ni < 4; ni++) {
        int r = wc*64 + ni*16 + (lane & 15);
        int u = (kk*4 + (lane >> 4)) ^ (r & 7);
        b[ni] = *(const short8*)(LB + r*64 + u*8);
      }
#pragma unroll
      for (int mi = 0; mi < 4; mi++)
#pragma unroll
        for (int ni = 0; ni < 4; ni++)
          acc[mi][ni] = __builtin_amdgcn_mfma_f32_16x16x32_bf16(a[mi], b[ni], acc[mi][ni], 0, 0, 0);
    }
    BARRIER();
  }

  const float* w2b_e = w2b + e * DD;
#pragma unroll
  for (int mi = 0; mi < 4; mi++) {
    int trb = wr*64 + mi*16 + ((lane >> 4) << 2);
#pragma unroll
    for (int j = 0; j < 4; j++) {
      int tr = trb + j;
      if (row0 + tr < cnt) {
        int pair = s_pair[tr];
        int t = pair >> 1;
        float gt = gates[pair];
        float* orow = out + (size_t)t * DD;
#pragma unroll
        for (int ni = 0; ni < 4; ni++) {
          int d = d0 + wc*64 + ni*16 + (lane & 15);
          float v = acc[mi][ni][j] * gt;
          if (addbias) v += w2b_e[d] * gt;
          atomicAdd(orow + d, v);
        }
      }
    }
  }
}

// ================= legacy f32 fallback (small ws) =================
__global__ __launch_bounds__(256, 2) void stage_a_f32(
    const float* __restrict__ x, const float* __restrict__ wgw, const float* __restrict__ wgb,
    const float* __restrict__ w1w, const float* __restrict__ w1b,
    const int* __restrict__ counts, const int* __restrict__ lists,
    short* __restrict__ hbuf, int f0chunk, int Fc) {

  const int e = blockIdx.z;
  const int cnt = counts[e];
  const int row0 = blockIdx.x * 128;
  if (row0 >= cnt) return;
  const int fc0 = blockIdx.y * 128;
  const int fg0 = f0chunk + fc0;

  __shared__ float lA[128 * 32];
  __shared__ float lBg[128 * 32];
  __shared__ float lB1[128 * 32];
  __shared__ int s_pair[128];

  const int tid = threadIdx.x;
  const int wid = tid >> 6;
  const int lane = tid & 63;

  if (tid < 128) {
    int r = row0 + tid;
    s_pair[tid] = (r < cnt) ? lists[e*TOK + r] : 0;
  }
  __syncthreads();

  const float* aSrc[4]; const float* gSrc[4]; const float* oSrc[4];
#pragma unroll
  for (int p = 0; p < 4; p++) {
    int j = p * 256 + tid;
    int r = j >> 3;
    int sl = (j & 7) ^ (r & 7);
    aSrc[p] = x + (size_t)(s_pair[r] >> 1) * DD + sl * 4;
    gSrc[p] = wgw + ((size_t)e * FF + fg0 + r) * DD + sl * 4;
    oSrc[p] = w1w + ((size_t)e * FF + fg0 + r) * DD + sl * 4;
  }

  f32x4 accg[4][4] = {}; f32x4 acc1[4][4] = {};
  const int wr = wid >> 1, wc = wid & 1;

  for (int k0 = 0; k0 < DD; k0 += 32) {
#pragma unroll
    for (int p = 0; p < 4; p++) async16(aSrc[p] + k0, &lA[p*1024 + wid*256]);
#pragma unroll
    for (int p = 0; p < 4; p++) async16(gSrc[p] + k0, &lBg[p*1024 + wid*256]);
#pragma unroll
    for (int p = 0; p < 4; p++) async16(oSrc[p] + k0, &lB1[p*1024 + wid*256]);
    __syncthreads();

    short8 a[4], bg[4], b1[4];
#pragma unroll
    for (int mi = 0; mi < 4; mi++) {
      int r = wr*64 + mi*16 + (lane & 15);
      int g2 = (lane >> 4) * 2;
      const f32x4* Ar = (const f32x4*)&lA[r * 32];
      a[mi] = cvt8(Ar[g2 ^ (r & 7)], Ar[(g2 + 1) ^ (r & 7)]);
    }
#pragma unroll
    for (int ni = 0; ni < 4; ni++) {
      int r = wc*64 + ni*16 + (lane & 15);
      int g2 = (lane >> 4) * 2;
      const f32x4* Bg = (const f32x4*)&lBg[r * 32];
      const f32x4* B1 = (const f32x4*)&lB1[r * 32];
      bg[ni] = cvt8(Bg[g2 ^ (r & 7)], Bg[(g2 + 1) ^ (r & 7)]);
      b1[ni] = cvt8(B1[g2 ^ (r & 7)], B1[(g2 + 1) ^ (r & 7)]);
    }
#pragma unroll
    for (int mi = 0; mi < 4; mi++)
#pragma unroll
      for (int ni = 0; ni < 4; ni++) {
        accg[mi][ni] = __builtin_amdgcn_mfma_f32_16x16x32_bf16(a[mi], bg[ni], accg[mi][ni], 0, 0, 0);
        acc1[mi][ni] = __builtin_amdgcn_mfma_f32_16x16x32_bf16(a[mi], b1[ni], acc1[mi][ni], 0, 0, 0);
      }
    __syncthreads();
  }

  const float* wgb_e = wgb + e * FF;
  const float* w1b_e = w1b + e * FF;
#pragma unroll
  for (int mi = 0; mi < 4; mi++) {
    int trb = wr*64 + mi*16 + ((lane >> 4) << 2);
#pragma unroll
    for (int ni = 0; ni < 4; ni++) {
      int c = wc*64 + ni*16 + (lane & 15);
      float bgv = wgb_e[fg0 + c];
      float b1v = w1b_e[fg0 + c];
#pragma unroll
      for (int j = 0; j < 4; j++) {
        int tr = trb + j;
        if (row0 + tr < cnt) {
          int pair = s_pair[tr];
          float hg = accg[mi][ni][j] + bgv;
          float h1 = acc1[mi][ni][j] + b1v;
          float gl = 0.5f * hg * (1.f + erff(hg * 0.70710678118f));
          hbuf[(size_t)pair * Fc + fc0 + c] = bfc(gl * h1);
        }
      }
    }
  }
}

__global__ __launch_bounds__(256, 2) void stage_b_f32(
    const short* __restrict__ hbuf, const float* __restrict__ w2w, const float* __restrict__ w2b,
    const int* __restrict__ counts, const int* __restrict__ lists, const float* __restrict__ gates,
    float* __restrict__ out, int f0chunk, int Fc, int addbias) {

  const int e = blockIdx.z;
  const int cnt = counts[e];
  const int row0 = blockIdx.x * 128;
  if (row0 >= cnt) return;
  const int d0 = blockIdx.y * 128;

  __shared__ short lA[128 * 64];
  __shared__ float lB[128 * 64];
  __shared__ int s_pair[128];

  const int tid = threadIdx.x;
  const int wid = tid >> 6;
  const int lane = tid & 63;

  if (tid < 128) {
    int r = row0 + tid;
    s_pair[tid] = (r < cnt) ? lists[e*TOK + r] : 0;
  }
  __syncthreads();

  const short* aSrc[4];
#pragma unroll
  for (int p = 0; p < 4; p++) {
    int j = p * 256 + tid;
    int r = j >> 3;
    int sl = (j & 7) ^ (r & 7);
    aSrc[p] = hbuf + (size_t)s_pair[r] * Fc + sl * 8;
  }
  const float* bSrc[8];
#pragma unroll
  for (int p = 0; p < 8; p++) {
    int j = p * 256 + tid;
    int r = j >> 4;
    int sl = (j & 15) ^ (r & 7);
    bSrc[p] = w2w + ((size_t)e * DD + d0 + r) * FF + f0chunk + sl * 4;
  }

  f32x4 acc[4][4] = {};
  const int wr = wid >> 1, wc = wid & 1;

  for (int kf = 0; kf < Fc; kf += 64) {
#pragma unroll
    for (int p = 0; p < 4; p++) async16(aSrc[p] + kf, &lA[p*2048 + wid*512]);
#pragma unroll
    for (int p = 0; p < 8; p++) async16(bSrc[p] + kf, &lB[p*1024 + wid*256]);
    __syncthreads();

#pragma unroll
    for (int kk = 0; kk < 2; kk++) {
      short8 a[4]; short8 b[4];
#pragma unroll
      for (int mi = 0; mi < 4; mi++) {
        int r = wr*64 + mi*16 + (lane & 15);
        int u = (kk*4 + (lane >> 4)) ^ (r & 7);
        a[mi] = ((const short8*)(lA + r * 64))[u];
      }
#pragma unroll
      for (int ni = 0; ni < 4; ni++) {
        int r = wc*64 + ni*16 + (lane & 15);
        int g2 = (kk*4 + (lane >> 4)) * 2;
        const f32x4* Br = (const f32x4*)(lB + r * 64);
        b[ni] = cvt8(Br[g2 ^ (r & 7)], Br[(g2 + 1) ^ (r & 7)]);
      }
#pragma unroll
      for (int mi = 0; mi < 4; mi++)
#pragma unroll
        for (int ni = 0; ni < 4; ni++)
          acc[mi][ni] = __builtin_amdgcn_mfma_f32_16x16x32_bf16(a[mi], b[ni], acc[mi][ni], 0, 0, 0);
    }
    __syncthreads();
  }

  const float* w2b_e = w2b + e * DD;
#pragma unroll
  for (int mi = 0; mi < 4; mi++) {
    int trb = wr*64 + mi*16 + ((lane >> 4) << 2);
#pragma unroll
    for (int j = 0; j < 4; j++) {
      int tr = trb + j;
      if (row0 + tr < cnt) {
        int pair = s_pair[tr];
        int t = pair >> 1;
        float gt = gates[pair];
        float* orow = out + (size_t)t * DD;
#pragma unroll
        for (int ni = 0; ni < 4; ni++) {
          int d = d0 + wc*64 + ni*16 + (lane & 15);
          float v = acc[mi][ni][j] * gt;
          if (addbias) v += w2b_e[d] * gt;
          atomicAdd(orow + d, v);
        }
      }
    }
  }
}

extern "C" void kernel_launch(void* const* d_in, const int* in_sizes, int n_in,
                              void* d_out, int out_size, void* d_ws, size_t ws_size,
                              hipStream_t stream) {
  const float* x   = (const float*)d_in[0];
  const float* rw  = (const float*)d_in[1];
  const float* w1w = (const float*)d_in[2];
  const float* w1b = (const float*)d_in[3];
  const float* w2w = (const float*)d_in[4];
  const float* w2b = (const float*)d_in[5];
  const float* wgw = (const float*)d_in[6];
  const float* wgb = (const float*)d_in[7];
  float* out = (float*)d_out;

  char* ws = (char*)d_ws;
  size_t off = 0;
  int* counts = (int*)(ws + off); off += 128;
  int* lists  = (int*)(ws + off); off += (size_t)EE * TOK * 4;
  float* gates = (float*)(ws + off); off += (size_t)NPAIR * 4;
  const size_t base0 = off;

  const size_t WELEM = (size_t)EE * FF * DD;
  const size_t bf_need = base0 + (size_t)TOK*DD*2 + 3*WELEM*2;

  hipMemsetAsync(counts, 0, 128, stream);
  hipMemsetAsync(out, 0, (size_t)TOK * DD * 4, stream);

  const int cands[6] = {4096, 2048, 1024, 512, 256, 128};

  if (bf_need + (size_t)NPAIR * 128 * 2 <= ws_size) {
    // ---- bf16 path ----
    off = base0;
    short* xb   = (short*)(ws + off); off += (size_t)TOK * DD * 2;
    short* wgwb = (short*)(ws + off); off += WELEM * 2;
    short* w1wb = (short*)(ws + off); off += WELEM * 2;
    short* w2wb = (short*)(ws + off); off += WELEM * 2;
    short* hbuf = (short*)(ws + off);

    int Fc = 128;
    for (int i = 0; i < 6; i++)
      if (off + (size_t)NPAIR * cands[i] * 2 <= ws_size) { Fc = cands[i]; break; }

    router_kernel<<<dim3(TOK), dim3(64), 0, stream>>>(x, rw, counts, lists, gates, xb);
    cvt_bf16_kernel<<<dim3(2048), dim3(256), 0, stream>>>(wgw, wgwb, (int)(WELEM/8));
    cvt_bf16_kernel<<<dim3(2048), dim3(256), 0, stream>>>(w1w, w1wb, (int)(WELEM/8));
    cvt_bf16_kernel<<<dim3(2048), dim3(256), 0, stream>>>(w2w, w2wb, (int)(WELEM/8));

    for (int f0 = 0; f0 < FF; f0 += Fc) {
      dim3 ga(32, Fc / 128, EE);                 // 256-row tiles
      stage_a_bf<<<ga, dim3(512), 0, stream>>>(xb, wgwb, wgb, w1wb, w1b, counts, lists, hbuf, f0, Fc);
      dim3 gb(64, DD / 128, EE);
      stage_b_bf<<<gb, dim3(256), 0, stream>>>(hbuf, w2wb, w2b, counts, lists, gates, out, f0, Fc, f0 == 0);
    }
  } else {
    // ---- legacy f32 path ----
    short* xb_dummy = nullptr; (void)xb_dummy;
    short* hbuf = (short*)(ws + base0);
    int Fc = 128;
    for (int i = 0; i < 6; i++)
      if (base0 + (size_t)NPAIR * cands[i] * 2 <= ws_size) { Fc = cands[i]; break; }

    // router still needs an xb target; reuse hbuf tail is unsafe -> use gates-adjacent scratch.
    // Legacy path: write xb into hbuf area temporarily is NOT safe (overwritten), so allocate
    // from the end of workspace if possible, else point at hbuf (never read by f32 path).
    short* xb = (short*)(ws + base0);  // f32 path never reads xb; router write target must be valid
    router_kernel<<<dim3(TOK), dim3(64), 0, stream>>>(x, rw, counts, lists, gates, xb);

    for (int f0 = 0; f0 < FF; f0 += Fc) {
      dim3 ga(64, Fc / 128, EE);
      stage_a_f32<<<ga, dim3(256), 0, stream>>>(x, wgw, wgb, w1w, w1b, counts, lists, hbuf, f0, Fc);
      dim3 gb(64, DD / 128, EE);
      stage_b_f32<<<gb, dim3(256), 0, stream>>>(hbuf, w2w, w2b, counts, lists, gates, out, f0, Fc, f0 == 0);
    }
  }
}